// Round 5
// baseline (516.453 us; speedup 1.0000x reference)
//
#include <hip/hip_runtime.h>
#include <hip/hip_fp16.h>

#define N_NODES 100000
#define N_EDGES 1600000
#define N_REL 4

// ---------------------------------------------------------------------------
// fp32 -> fp16 table conversion (vectorized x4)
// ---------------------------------------------------------------------------
__global__ __launch_bounds__(256) void cvt_kernel(const float* __restrict__ in,
                                                  __half* __restrict__ out,
                                                  int n4) {
  int i = blockIdx.x * 256 + threadIdx.x;
  if (i >= n4) return;
  float4 v = ((const float4*)in)[i];
  __half2* o = (__half2*)(out + (long)i * 4);
  o[0] = __floats2half2_rn(v.x, v.y);
  o[1] = __floats2half2_rn(v.z, v.w);
}

// ---------------------------------------------------------------------------
// CSR build: count -> alloc (block scan + bump pointer) -> fill
// ---------------------------------------------------------------------------
__global__ __launch_bounds__(256) void count_kernel(const int* __restrict__ dst,
                                                    const int* __restrict__ et,
                                                    int* __restrict__ cnt,
                                                    int E, int N) {
  int e = blockIdx.x * 256 + threadIdx.x;
  if (e >= E) return;
  atomicAdd(&cnt[et[e] * N + dst[e]], 1);
}

__global__ __launch_bounds__(256) void alloc_kernel(const int* __restrict__ cnt,
                                                    int* __restrict__ off,
                                                    int* __restrict__ cur,
                                                    int* __restrict__ top,
                                                    int RN) {
  __shared__ int s[256];
  __shared__ int base;
  const int i = blockIdx.x * 256 + threadIdx.x;
  const int c = (i < RN) ? cnt[i] : 0;
  s[threadIdx.x] = c;
  __syncthreads();
  // Hillis-Steele inclusive scan
  for (int d = 1; d < 256; d <<= 1) {
    int v = (threadIdx.x >= d) ? s[threadIdx.x - d] : 0;
    __syncthreads();
    s[threadIdx.x] += v;
    __syncthreads();
  }
  if (threadIdx.x == 255) base = atomicAdd(top, s[255]);
  __syncthreads();
  if (i < RN) {
    int excl = base + s[threadIdx.x] - c;
    off[i] = excl;
    cur[i] = excl;
  }
}

__global__ __launch_bounds__(256) void fill_kernel(
    const int* __restrict__ src, const int* __restrict__ dst,
    const int* __restrict__ et, int* __restrict__ cur, int* __restrict__ eidx,
    int E, int N) {
  int e = blockIdx.x * 256 + threadIdx.x;
  if (e >= E) return;
  int seg = et[e] * N + dst[e];
  int pos = atomicAdd(&cur[seg], 1);
  eidx[pos] = src[e];
}

// ---------------------------------------------------------------------------
// Fused per-layer kernel: gather(fp16) + mean per relation + transform.
// Phase 1: thread = (node, relation, 16B granule of 8 halves). Independent
//   float4 gathers (2-way unrolled), fp32 accumulate, mean -> LDS.
// Phase 2: thread = (node, out-channel). W/root from global (L1-resident),
//   sAgg/sX broadcast from LDS. Output fp16 (hidden) or fp32 (final).
// ---------------------------------------------------------------------------
template <int DIN, int DOUT, bool RELU, bool OUT_HALF>
__global__ __launch_bounds__(256, 8) void gather_transform_kernel(
    const __half* __restrict__ xh, const int* __restrict__ cnt,
    const int* __restrict__ off, const int* __restrict__ eidx,
    const float* __restrict__ W, const float* __restrict__ root,
    const float* __restrict__ bias, void* __restrict__ outp, int N) {
  constexpr int G = DIN / 8;              // 16B granules per feature row
  constexpr int GN = 256 / (N_REL * G);   // nodes per block: 32 (din16), 16 (din32)
  __shared__ float sAgg[GN][N_REL][DIN];
  __shared__ float sX[GN][DIN];

  // ---- phase 1: gather + mean ----
  {
    const int g = threadIdx.x % G;
    const int r = (threadIdx.x / G) % N_REL;
    const int ni = threadIdx.x / (G * N_REL);
    const int node = blockIdx.x * GN + ni;
    if (node < N) {
      const float4* xv = (const float4*)xh;  // 16 B = 8 halves
      if (r == 0) {  // stage this node's own row
        union { float4 f; __half2 h[4]; } u;
        u.f = xv[(long)node * G + g];
        float* d = &sX[ni][g * 8];
#pragma unroll
        for (int k = 0; k < 4; k++) {
          float2 f2 = __half22float2(u.h[k]);
          d[2 * k] = f2.x;
          d[2 * k + 1] = f2.y;
        }
      }
      const int seg = r * N + node;
      const int c = cnt[seg];
      const int st = off[seg];
      float s[8] = {0.f, 0.f, 0.f, 0.f, 0.f, 0.f, 0.f, 0.f};
      int e = 0;
      for (; e + 2 <= c; e += 2) {  // two independent gathers in flight
        int s0 = eidx[st + e], s1 = eidx[st + e + 1];
        union { float4 f; __half2 h[4]; } u0, u1;
        u0.f = xv[(long)s0 * G + g];
        u1.f = xv[(long)s1 * G + g];
#pragma unroll
        for (int k = 0; k < 4; k++) {
          float2 a = __half22float2(u0.h[k]);
          float2 b = __half22float2(u1.h[k]);
          s[2 * k] += a.x + b.x;
          s[2 * k + 1] += a.y + b.y;
        }
      }
      if (e < c) {
        union { float4 f; __half2 h[4]; } u0;
        u0.f = xv[(long)eidx[st + e] * G + g];
#pragma unroll
        for (int k = 0; k < 4; k++) {
          float2 a = __half22float2(u0.h[k]);
          s[2 * k] += a.x;
          s[2 * k + 1] += a.y;
        }
      }
      const float ic = (c > 0) ? 1.f / (float)c : 0.f;
      float* d = &sAgg[ni][r][g * 8];
#pragma unroll
      for (int k = 0; k < 8; k++) d[k] = s[k] * ic;
    }
  }
  __syncthreads();

  // ---- phase 2: dense transform ----
  constexpr int NPP = 256 / DOUT;   // nodes per pass
  constexpr int PASSES = GN / NPP;  // 2 / 4 / 4
  const int oc = threadIdx.x % DOUT;
  const int nj0 = threadIdx.x / DOUT;
#pragma unroll
  for (int p = 0; p < PASSES; p++) {
    const int nj = nj0 + p * NPP;
    const int node2 = blockIdx.x * GN + nj;
    if (node2 < N) {
      float acc = bias[oc];
#pragma unroll
      for (int k = 0; k < DIN; k++) acc += sX[nj][k] * root[k * DOUT + oc];
#pragma unroll
      for (int r = 0; r < N_REL; r++) {
#pragma unroll
        for (int k = 0; k < DIN; k++)
          acc += sAgg[nj][r][k] * W[(r * DIN + k) * DOUT + oc];
      }
      if (RELU) acc = fmaxf(acc, 0.f);
      if (OUT_HALF)
        ((__half*)outp)[(long)node2 * DOUT + oc] = __float2half(acc);
      else
        ((float*)outp)[(long)node2 * DOUT + oc] = acc;
    }
  }
}

// ---------------------------------------------------------------------------
// Host launch
// ---------------------------------------------------------------------------
static inline size_t align256(size_t v) { return (v + 255) & ~(size_t)255; }

extern "C" void kernel_launch(void* const* d_in, const int* in_sizes, int n_in,
                              void* d_out, int out_size, void* d_ws,
                              size_t ws_size, hipStream_t stream) {
  const int N = N_NODES;
  const int E = N_EDGES;
  const int RN = N_REL * N;

  const float* x = (const float*)d_in[0];
  const int* edge_index = (const int*)d_in[1];
  const int* et = (const int*)d_in[2];
  const float* W1 = (const float*)d_in[3];
  const float* root1 = (const float*)d_in[4];
  const float* b1 = (const float*)d_in[5];
  const float* W2 = (const float*)d_in[6];
  const float* root2 = (const float*)d_in[7];
  const float* b2 = (const float*)d_in[8];
  const float* W3 = (const float*)d_in[9];
  const float* root3 = (const float*)d_in[10];
  const float* b3 = (const float*)d_in[11];

  const int* src = edge_index;      // edge_index[0]
  const int* dst = edge_index + E;  // edge_index[1]

  // Workspace carve-up (~24 MB)
  char* ws = (char*)d_ws;
  size_t off_b = 0;
  int* cnt = (int*)(ws + off_b);
  off_b = align256(off_b + (size_t)RN * 4);
  int* off = (int*)(ws + off_b);
  off_b = align256(off_b + (size_t)RN * 4);
  int* cur = (int*)(ws + off_b);
  off_b = align256(off_b + (size_t)RN * 4);
  int* top = (int*)(ws + off_b);
  off_b = align256(off_b + 256);
  int* eidx = (int*)(ws + off_b);
  off_b = align256(off_b + (size_t)E * 4);
  __half* xh = (__half*)(ws + off_b);
  off_b = align256(off_b + (size_t)N * 16 * 2);
  __half* h1 = (__half*)(ws + off_b);
  off_b = align256(off_b + (size_t)N * 16 * 2);
  __half* h2 = (__half*)(ws + off_b);
  off_b = align256(off_b + (size_t)N * 32 * 2);
  (void)ws_size;

  float* out = (float*)d_out;

  // --- build CSR (edge structure shared by all 3 layers) + fp16 x ---
  hipMemsetAsync(cnt, 0, (size_t)RN * 4, stream);
  hipMemsetAsync(top, 0, 256, stream);
  cvt_kernel<<<(N * 16 / 4 + 255) / 256, 256, 0, stream>>>(x, xh, N * 16 / 4);
  count_kernel<<<(E + 255) / 256, 256, 0, stream>>>(dst, et, cnt, E, N);
  alloc_kernel<<<(RN + 255) / 256, 256, 0, stream>>>(cnt, off, cur, top, RN);
  fill_kernel<<<(E + 255) / 256, 256, 0, stream>>>(src, dst, et, cur, eidx, E,
                                                   N);

  // --- layer 1: 16 -> 16, relu, fp16 out ---
  {
    constexpr int GN = 256 / (N_REL * 2);  // 32
    gather_transform_kernel<16, 16, true, true>
        <<<(N + GN - 1) / GN, 256, 0, stream>>>(xh, cnt, off, eidx, W1, root1,
                                                b1, h1, N);
  }
  // --- layer 2: 16 -> 32, relu, fp16 out ---
  {
    constexpr int GN = 256 / (N_REL * 2);  // 32
    gather_transform_kernel<16, 32, true, true>
        <<<(N + GN - 1) / GN, 256, 0, stream>>>(h1, cnt, off, eidx, W2, root2,
                                                b2, h2, N);
  }
  // --- layer 3: 32 -> 64, no relu, fp32 out ---
  {
    constexpr int GN = 256 / (N_REL * 4);  // 16
    gather_transform_kernel<32, 64, false, false>
        <<<(N + GN - 1) / GN, 256, 0, stream>>>(h2, cnt, off, eidx, W3, root3,
                                                b3, out, N);
  }
}